// Round 7
// baseline (283.071 us; speedup 1.0000x reference)
//
#include <hip/hip_runtime.h>
#include <hip/hip_bf16.h>

// GraphConvNorm: scatter-mean by (row*7+edge_type) -> [N,896]@[896,128] -> BatchNorm.
// N=100000, C=128, E=700000. x/w/gamma/beta f32, indices auto int32/int64, out f32.
// r13 post-mortem: occ 48->74% gave 0 gain (101 vs 102us) -> shared-resource wall:
// (a) phase-2 re-reads wp per wave: 28KB x 8 x 6250 blocks = 1.4GB L2 traffic
//     (~14 TB/s of the 34.5 L2 ceiling for a 229KB matrix);
// (b) VALU issue ~saturated (73%): 8x 64-bit per-lane addr calc for WAVE-UNIFORM
//     edge bases + ds_bpermute shfls where readlane (SALU path) suffices.
// r14: TNODES=32 w/ 1024-thr/16-wave blocks (LDS 57.9KB x2 blocks/CU = 32 waves/CU,
// 100% occ; W traffic halved to 0.7GB; phase-2 B-load issue per node halved);
// scalarized gather (readlane -> SGPR base + shared voffset, switch keys on SGPR);
// float2 accumulators (packed adds). Phase-1 pipeline (2 nodes/wave, clamped
// branch-free batch-8) unchanged from r13.
// ws: xb 25.6MB + wp 0.23 + meta 19.2MB + ovf 2.8 + stats 8KB.

typedef float  f32x4  __attribute__((ext_vector_type(4)));
typedef float  f32x2  __attribute__((ext_vector_type(2)));
typedef short  short8 __attribute__((ext_vector_type(8)));
typedef __bf16 bf16x8 __attribute__((ext_vector_type(8)));

union BFrag { uint4 q; short8 s; bf16x8 b; unsigned int u[4]; };

__device__ inline unsigned short f2bfbits(float f) {
    union { float f; unsigned int u; } v; v.f = f;
    unsigned int u = v.u;
    u += 0x7fffu + ((u >> 16) & 1u);   // RNE
    return (unsigned short)(u >> 16);
}
__device__ inline unsigned int pk_bf16(float lo, float hi) {
    float2 f; f.x = lo; f.y = hi;
    union { __hip_bfloat162 h; unsigned int u; } v;
    v.h = __float22bfloat162_rn(f);
    return v.u;
}
__device__ inline float bflo(unsigned int p) {
    union { unsigned int u; float f; } v; v.u = p << 16; return v.f;
}
__device__ inline float bfhi(unsigned int p) {
    union { unsigned int u; float f; } v; v.u = p & 0xffff0000u; return v.f;
}

#define BUCKET_CAP 32
#define ROWW 48          // meta row: 0-6 ovf-cnt, 7 fill, 8-39 payload, 40-47 pad
#define LROW 452         // LDS row u32 (448 data + 4 pad)
#define TNODES 32

// ---- W [7*128,128] f32 -> bf16 in MFMA B-frag order: [t][nt][kc][lane][j] ----
__global__ void pack_w(const float* __restrict__ w, short8* __restrict__ wp)
{
    int u = blockIdx.x * 256 + threadIdx.x;
    if (u >= 7 * 8 * 4 * 64) return;
    int lane = u & 63, kc = (u >> 6) & 3, nt = (u >> 8) & 7, t = u >> 11;
    int quad = lane >> 4, lr = lane & 15;
    short8 s;
#pragma unroll
    for (int j = 0; j < 8; ++j)
        s[j] = (short)f2bfbits(w[(size_t)(t * 128 + kc * 32 + quad * 8 + j) * 128
                                 + nt * 16 + lr]);
    wp[u] = s;
}

// ---- x [N,128] f32 -> bf16 packed u32 pairs: xbu[n*64+l] = ch(2l, 2l+1) ----
__global__ __launch_bounds__(256) void pack_x(const float* __restrict__ x,
                                              unsigned int* __restrict__ xbu,
                                              long total4)
{
    for (size_t v = (size_t)blockIdx.x * 256 + threadIdx.x; v < (size_t)total4;
         v += (size_t)gridDim.x * 256) {
        f32x4 t = *(const f32x4*)(x + v * 4);
        xbu[v * 2]     = pk_bf16(t[0], t[1]);
        xbu[v * 2 + 1] = pk_bf16(t[2], t[3]);
    }
}

// ---- index width autodetect ----
__global__ void flag_k(const int* __restrict__ row, int* __restrict__ flag)
{
    if (threadIdx.x == 0 && blockIdx.x == 0) {
        int s = 0;
#pragma unroll
        for (int i = 1; i < 64; i += 2) s |= row[i];
        flag[0] = (s == 0) ? 1 : 0;
    }
}
__device__ inline int idx_at(const int* __restrict__ p, int e, int mode) {
    return p[mode ? (e << 1) : e];
}

// ---- bucket into meta rows; 1 atomic/edge; t=6 dead (self slot overwritten) ----
__global__ void edge_k(const int* __restrict__ row, const int* __restrict__ col,
                       const int* __restrict__ et, const int* __restrict__ flag,
                       unsigned int* __restrict__ meta, int* __restrict__ ovf,
                       int* __restrict__ novf, int E, int N)
{
    int e = blockIdx.x * blockDim.x + threadIdx.x;
    if (e >= E) return;
    const int mode = flag[0];
    int r = idx_at(row, e, mode);
    int c = idx_at(col, e, mode);
    int t = idx_at(et,  e, mode);
    if ((unsigned)r >= (unsigned)N || (unsigned)c >= (unsigned)N || (unsigned)t >= 6u)
        return;
    unsigned pos = atomicAdd(&meta[(size_t)r * ROWW + 7], 1u);
    if (pos < BUCKET_CAP) {
        meta[(size_t)r * ROWW + 8 + pos] = (unsigned)((c << 3) | t);
    } else {
        atomicAdd(&meta[(size_t)r * ROWW + t], 1u);   // overflow-only type count
        ovf[atomicAdd(novf, 1)] = e;
    }
}

// ---- fused gather(xb)->means->LDS->GEMM(wp)->out + BN stats. ----
// 32 nodes/block, 16 waves (1024 thr): 2 nodes/wave phase-1,
// phase-2 wave (g,nt) = (wv>>3, wv&7): [16 nodes x 16 ch].
__global__ __launch_bounds__(1024, 8) void fused_k(
    const unsigned int* __restrict__ meta, const unsigned int* __restrict__ xbu,
    const uint4* __restrict__ wpq, float* __restrict__ out,
    float* __restrict__ statsR, int N)
{
    __shared__ unsigned int cold[TNODES * LROW];   // 57856 B; 2 blocks/CU
    const int tid  = threadIdx.x;
    const int l    = tid & 63;
    const int wv   = tid >> 6;                     // 0..15
    const int quad = l >> 4, lr = l & 15;
    const int tile = blockIdx.x * TNODES;
    const int base = tile + wv * 2;

    // ================= phase 1: per-node type-means (2 nodes/wave) =========
    unsigned mv = 0, self = 0;
    if (base < N) {
        mv   = (l < 40) ? meta[(size_t)base * ROWW + l] : 0u;
        self = xbu[(size_t)base * 64 + l];
    }
#pragma unroll
    for (int i = 0; i < 2; ++i) {
        const int r = base + i;
        if (r < N) {
            const unsigned fl =
                (unsigned)__builtin_amdgcn_readlane((int)mv, 7);
            const int nE = (int)min(fl, (unsigned)BUCKET_CAP);   // SGPR
            const unsigned sv   = self;
            const unsigned mcur = mv;

            f32x2 acc[6];
#pragma unroll
            for (int t = 0; t < 6; ++t) acc[t] = (f32x2){0.f, 0.f};

            // batch 0: 8 clamped loads, scalar base (readlane -> SGPR) ->
            // global_load with SGPR base + shared voffset; all 8 in flight.
            unsigned q[8]; int pt[8];
            if (nE > 0) {
#pragma unroll
                for (int j = 0; j < 8; ++j) {
                    int pb = __builtin_amdgcn_readlane((int)mcur,
                                                       8 + min(j, nE - 1));
                    pt[j] = pb & 7;
                    q[j]  = xbu[(size_t)(pb >> 3) * 64 + l];
                }
            }
            // prefetch next node metadata under the edge-load latency
            if (i == 0 && r + 1 < N) {
                mv   = (l < 40) ? meta[(size_t)(r + 1) * ROWW + l] : 0u;
                self = xbu[(size_t)(r + 1) * 64 + l];
            }
            if (nE > 0) {
#pragma unroll
                for (int j = 0; j < 8; ++j) {
                    unsigned qq = (j < nE) ? q[j] : 0u;   // zeroed dup: adds 0
                    f32x2 v; v.x = bflo(qq); v.y = bfhi(qq);
                    switch (pt[j]) {                      // SGPR key
                        case 0: acc[0] += v; break;
                        case 1: acc[1] += v; break;
                        case 2: acc[2] += v; break;
                        case 3: acc[3] += v; break;
                        case 4: acc[4] += v; break;
                        default: acc[5] += v; break;
                    }
                }
                // rare tail: degree > 8
                for (int k = 8; k < nE; k += 8) {
                    const int rem = nE - k;
#pragma unroll
                    for (int j = 0; j < 8; ++j) {
                        int pb = __builtin_amdgcn_readlane((int)mcur,
                                     8 + k + min(j, rem - 1));
                        pt[j] = pb & 7;
                        q[j]  = xbu[(size_t)(pb >> 3) * 64 + l];
                    }
#pragma unroll
                    for (int j = 0; j < 8; ++j) {
                        unsigned qq = (j < rem) ? q[j] : 0u;
                        f32x2 v; v.x = bflo(qq); v.y = bfhi(qq);
                        switch (pt[j]) {
                            case 0: acc[0] += v; break;
                            case 1: acc[1] += v; break;
                            case 2: acc[2] += v; break;
                            case 3: acc[3] += v; break;
                            case 4: acc[4] += v; break;
                            default: acc[5] += v; break;
                        }
                    }
                }
            }

            // per-type counts: ballot over in-bucket payloads (+ rare ovf words)
            const bool inb = (l >= 8) && (l < 8 + nE);
            int c0 = (int)__popcll(__ballot(inb && ((mcur & 7u) == 0u)));
            int c1 = (int)__popcll(__ballot(inb && ((mcur & 7u) == 1u)));
            int c2 = (int)__popcll(__ballot(inb && ((mcur & 7u) == 2u)));
            int c3 = (int)__popcll(__ballot(inb && ((mcur & 7u) == 3u)));
            int c4 = (int)__popcll(__ballot(inb && ((mcur & 7u) == 4u)));
            int c5 = (int)__popcll(__ballot(inb && ((mcur & 7u) == 5u)));
            if (fl > (unsigned)BUCKET_CAP) {        // essentially never
                c0 += __builtin_amdgcn_readlane((int)mcur, 0);
                c1 += __builtin_amdgcn_readlane((int)mcur, 1);
                c2 += __builtin_amdgcn_readlane((int)mcur, 2);
                c3 += __builtin_amdgcn_readlane((int)mcur, 3);
                c4 += __builtin_amdgcn_readlane((int)mcur, 4);
                c5 += __builtin_amdgcn_readlane((int)mcur, 5);
            }
            const float iv0 = 1.0f / (float)max(c0, 1);
            const float iv1 = 1.0f / (float)max(c1, 1);
            const float iv2 = 1.0f / (float)max(c2, 1);
            const float iv3 = 1.0f / (float)max(c3, 1);
            const float iv4 = 1.0f / (float)max(c4, 1);
            const float iv5 = 1.0f / (float)max(c5, 1);

            // means -> LDS (bf16 pairs); self slot (t=6) = xb row verbatim
            const int mrow = (wv * 2 + i) * LROW;
            cold[mrow + 0 * 64 + l] = pk_bf16(acc[0].x * iv0, acc[0].y * iv0);
            cold[mrow + 1 * 64 + l] = pk_bf16(acc[1].x * iv1, acc[1].y * iv1);
            cold[mrow + 2 * 64 + l] = pk_bf16(acc[2].x * iv2, acc[2].y * iv2);
            cold[mrow + 3 * 64 + l] = pk_bf16(acc[3].x * iv3, acc[3].y * iv3);
            cold[mrow + 4 * 64 + l] = pk_bf16(acc[4].x * iv4, acc[4].y * iv4);
            cold[mrow + 5 * 64 + l] = pk_bf16(acc[5].x * iv5, acc[5].y * iv5);
            cold[mrow + 6 * 64 + l] = sv;
        }
    }
    __syncthreads();

    // ==== phase 2: wave (g,nt): [16 nodes x 16 ch], 2 indep MFMA chains ====
    const int g  = wv >> 3;
    const int nt = wv & 7;
    const int arow = (g * 16 + lr) * LROW;
    f32x4 oa0 = (f32x4){0.f, 0.f, 0.f, 0.f};
    f32x4 oa1 = (f32x4){0.f, 0.f, 0.f, 0.f};
#pragma unroll
    for (int t = 0; t < 4; ++t)
#pragma unroll
        for (int kc = 0; kc < 4; ++kc) {
            BFrag a, b;
            const int ko = t * 64 + kc * 16 + quad * 4;
            a.q = *(const uint4*)&cold[arow + ko];
            b.q = wpq[(size_t)(((t * 8 + nt) * 4 + kc) * 64) + l];
            oa0 = __builtin_amdgcn_mfma_f32_16x16x32_bf16(a.b, b.b, oa0, 0, 0, 0);
        }
#pragma unroll
    for (int t = 4; t < 7; ++t)
#pragma unroll
        for (int kc = 0; kc < 4; ++kc) {
            BFrag a, b;
            const int ko = t * 64 + kc * 16 + quad * 4;
            a.q = *(const uint4*)&cold[arow + ko];
            b.q = wpq[(size_t)(((t * 8 + nt) * 4 + kc) * 64) + l];
            oa1 = __builtin_amdgcn_mfma_f32_16x16x32_bf16(a.b, b.b, oa1, 0, 0, 0);
        }
    // epilogue + fused BN stats. C/D: col=lr -> ch=nt*16+lr, row=quad*4+j
    float s = 0.f, s2 = 0.f;
    const int ch = nt * 16 + lr;
#pragma unroll
    for (int j = 0; j < 4; ++j) {
        int m = tile + g * 16 + quad * 4 + j;
        if (m < N) {
            float v = oa0[j] + oa1[j];
            out[(size_t)m * 128 + ch] = v;
            s += v; s2 += v * v;
        }
    }
    s  += __shfl_xor(s, 16);  s  += __shfl_xor(s, 32);   // reduce across quads
    s2 += __shfl_xor(s2, 16); s2 += __shfl_xor(s2, 32);
    if (l < 16) {
        float* st = statsR + (size_t)(blockIdx.x & 7) * 256;   // 8 replicas
        atomicAdd(&st[ch],       s);
        atomicAdd(&st[128 + ch], s2);
    }
}

// ---- overflow repair: matvec xb[c]@W[t]/cnt -> out AND stats (replica 0) ----
__global__ void ovf_k(const int* __restrict__ ovf, const int* __restrict__ novf,
                      const int* __restrict__ row, const int* __restrict__ col,
                      const int* __restrict__ et, const int* __restrict__ flag,
                      const unsigned int* __restrict__ xbu,
                      const unsigned int* __restrict__ meta,
                      const float* __restrict__ w,
                      float* __restrict__ out, float* __restrict__ statsR,
                      int nwaves)
{
    const int n = novf[0];
    if (n == 0) return;
    const int mode = flag[0];
    const int l = threadIdx.x & 63;
    for (int i = (blockIdx.x * 256 + threadIdx.x) >> 6; i < n; i += nwaves) {
        int e = ovf[i];
        int r = idx_at(row, e, mode);
        int c = idx_at(col, e, mode);
        int t = idx_at(et,  e, mode);
        // exact count = in-bucket ballot + overflow word
        unsigned mv = (l < 40) ? meta[(size_t)r * ROWW + l] : 0u;
        unsigned fl = __shfl(mv, 7);
        int nE = (int)min(fl, (unsigned)BUCKET_CAP);
        bool inb = (l >= 8) && (l < 8 + nE);
        int ct = (int)__popcll(__ballot(inb && ((int)(mv & 7u) == t)))
               + (int)__shfl(mv, t);
        float inv = 1.0f / (float)max(ct, 1);
        float d0 = 0.f, d1 = 0.f;
        for (int k = 0; k < 64; ++k) {
            unsigned xv = xbu[(size_t)c * 64 + k];
            float xlo = bflo(xv), xhi = bfhi(xv);
            const float* wr = w + (size_t)(t * 128 + 2 * k) * 128;
            d0 += xlo * wr[2 * l]     + xhi * wr[128 + 2 * l];
            d1 += xlo * wr[2 * l + 1] + xhi * wr[128 + 2 * l + 1];
        }
        d0 *= inv; d1 *= inv;
        float olo = atomicAdd(&out[(size_t)r * 128 + 2 * l],     d0);
        float ohi = atomicAdd(&out[(size_t)r * 128 + 2 * l + 1], d1);
        atomicAdd(&statsR[2 * l],           d0);
        atomicAdd(&statsR[128 + 2 * l],     d0 * (2.f * olo + d0));
        atomicAdd(&statsR[2 * l + 1],       d1);
        atomicAdd(&statsR[128 + 2 * l + 1], d1 * (2.f * ohi + d1));
    }
}

// ---- BN finalize: sums 8 stat replicas; coalesced vec4; no LDS ----
__global__ __launch_bounds__(256) void norm_k(
    float* __restrict__ out, const float* __restrict__ statsR,
    const float* __restrict__ gamma, const float* __restrict__ beta, int N)
{
    const int c0 = (threadIdx.x * 4) & 127;     // grid stride is mult. of 128 elems
    const float invN = 1.0f / (float)N;
    f32x4 sc, bi;
#pragma unroll
    for (int j = 0; j < 4; ++j) {
        int c = c0 + j;
        float sm = 0.f, sq = 0.f;
#pragma unroll
        for (int rep = 0; rep < 8; ++rep) {
            sm += statsR[rep * 256 + c];
            sq += statsR[rep * 256 + 128 + c];
        }
        float mean = sm * invN;
        float var  = sq * invN - mean * mean;
        float s = gamma[c] * rsqrtf(var + 1e-5f);
        sc[j] = s; bi[j] = beta[c] - mean * s;
    }
    const size_t nv = (size_t)N * 32;           // vec4 count
    for (size_t v = (size_t)blockIdx.x * 256 + threadIdx.x; v < nv;
         v += (size_t)gridDim.x * 256) {
        f32x4 x = *(f32x4*)(out + v * 4);
#pragma unroll
        for (int j = 0; j < 4; ++j) x[j] = x[j] * sc[j] + bi[j];
        *(f32x4*)(out + v * 4) = x;
    }
}

extern "C" void kernel_launch(void* const* d_in, const int* in_sizes, int n_in,
                              void* d_out, int out_size, void* d_ws, size_t ws_size,
                              hipStream_t stream)
{
    const float* x     = (const float*)d_in[0];
    const int*   row   = (const int*)d_in[1];
    const int*   col   = (const int*)d_in[2];
    const int*   etype = (const int*)d_in[3];
    const float* w     = (const float*)d_in[4];
    const float* gamma = (const float*)d_in[5];
    const float* beta  = (const float*)d_in[6];
    float* out = (float*)d_out;

    const int N = in_sizes[0] / 128;   // 100000
    const int E = in_sizes[1];         // 700000

    char* ws = (char*)d_ws;
    unsigned int* xbu   = (unsigned int*)ws;                             // N*64 u32
    short8*       wp    = (short8*)(ws + (size_t)N * 256);               // 229376 B
    unsigned int* meta  = (unsigned int*)((char*)wp + 7 * 8 * 4 * 64 * 16); // N*48 u32
    int*          ovf   = (int*)((char*)meta + (size_t)N * ROWW * 4 + 256); // E int
    float*        stats = (float*)((char*)ovf + (size_t)E * 4);          // 8*256 f32
    int*          flag  = (int*)((char*)stats + 8 * 256 * 4);            // 1 int
    int*          novf  = flag + 1;                                      // 1 int

    hipMemsetAsync(meta,  0, (size_t)N * ROWW * 4, stream);
    hipMemsetAsync(stats, 0, 8 * 256 * 4 + 8,      stream);

    flag_k<<<1, 64, 0, stream>>>(row, flag);
    pack_w<<<(7 * 8 * 4 * 64 + 255) / 256, 256, 0, stream>>>(w, wp);
    pack_x<<<2048, 256, 0, stream>>>(x, xbu, (long)N * 32);
    edge_k<<<(E + 255) / 256, 256, 0, stream>>>(row, col, etype, flag,
                                                meta, ovf, novf, E, N);
    fused_k<<<(N + TNODES - 1) / TNODES, 1024, 0, stream>>>(meta, xbu,
                                                            (const uint4*)wp, out,
                                                            stats, N);
    ovf_k<<<64, 256, 0, stream>>>(ovf, novf, row, col, etype, flag,
                                  xbu, meta, w, out, stats, 256);
    norm_k<<<2048, 256, 0, stream>>>(out, stats, gamma, beta, N);
}

// Round 8
// 262.705 us; speedup vs baseline: 1.0775x; 1.0775x over previous
//
#include <hip/hip_runtime.h>
#include <hip/hip_bf16.h>

// GraphConvNorm: scatter-mean by (row*7+edge_type) -> [N,896]@[896,128] -> BatchNorm.
// N=100000, C=128, E=700000. x/w/gamma/beta f32, indices auto int32/int64, out f32.
// Cross-round invariant (r11/r13/r14): fused_k gather pins at ~1.8 TB/s effective for
// random 256B reads regardless of occupancy (48-74%) / geometry -> machine random-line
// ceiling; gather floor = E*256B/1.9TBps ~= 90us; r13's 102us is ~90% of it.
// r14 (TNODES=32, 1024thr, SGPR-switch) regressed 102->125: barrier tail + scalar
// branch chains; W-L2-traffic theory falsified (halving it gained 0).
// r15: revert fused_k to r13 config (512thr/8wave, TNODES=16, VGPR switch);
// attack the unprofiled ~160us remainder: meta row 192B->one aligned 128B line
// (ROWW=32, CAP=31, fill@0, payload@1..31; ovf type-counts in separate cold 7N
// array) -> edge_k random line-RMWs 3->2 per edge, memset -6.4MB, meta fetch -20%.
// ws: xb 25.6MB + wp 0.23 + meta 12.8MB + ovfcnt 2.8MB + ovf 2.8 + stats 8KB.

typedef float  f32x4  __attribute__((ext_vector_type(4)));
typedef float  f32x2  __attribute__((ext_vector_type(2)));
typedef short  short8 __attribute__((ext_vector_type(8)));
typedef __bf16 bf16x8 __attribute__((ext_vector_type(8)));

union BFrag { uint4 q; short8 s; bf16x8 b; unsigned int u[4]; };

__device__ inline unsigned short f2bfbits(float f) {
    union { float f; unsigned int u; } v; v.f = f;
    unsigned int u = v.u;
    u += 0x7fffu + ((u >> 16) & 1u);   // RNE
    return (unsigned short)(u >> 16);
}
__device__ inline unsigned int pk_bf16(float lo, float hi) {
    float2 f; f.x = lo; f.y = hi;
    union { __hip_bfloat162 h; unsigned int u; } v;
    v.h = __float22bfloat162_rn(f);
    return v.u;
}
__device__ inline float bflo(unsigned int p) {
    union { unsigned int u; float f; } v; v.u = p << 16; return v.f;
}
__device__ inline float bfhi(unsigned int p) {
    union { unsigned int u; float f; } v; v.u = p & 0xffff0000u; return v.f;
}

#define BUCKET_CAP 31
#define ROWW 32          // meta row: w0 = fill, w1-31 = payload  (one 128B line)
#define LROW 452         // LDS row u32 (448 data + 4 pad)
#define TNODES 16

// ---- W [7*128,128] f32 -> bf16 in MFMA B-frag order: [t][nt][kc][lane][j] ----
__global__ void pack_w(const float* __restrict__ w, short8* __restrict__ wp)
{
    int u = blockIdx.x * 256 + threadIdx.x;
    if (u >= 7 * 8 * 4 * 64) return;
    int lane = u & 63, kc = (u >> 6) & 3, nt = (u >> 8) & 7, t = u >> 11;
    int quad = lane >> 4, lr = lane & 15;
    short8 s;
#pragma unroll
    for (int j = 0; j < 8; ++j)
        s[j] = (short)f2bfbits(w[(size_t)(t * 128 + kc * 32 + quad * 8 + j) * 128
                                 + nt * 16 + lr]);
    wp[u] = s;
}

// ---- x [N,128] f32 -> bf16 packed u32 pairs: xbu[n*64+l] = ch(2l, 2l+1) ----
__global__ __launch_bounds__(256) void pack_x(const float* __restrict__ x,
                                              unsigned int* __restrict__ xbu,
                                              long total4)
{
    for (size_t v = (size_t)blockIdx.x * 256 + threadIdx.x; v < (size_t)total4;
         v += (size_t)gridDim.x * 256) {
        f32x4 t = *(const f32x4*)(x + v * 4);
        xbu[v * 2]     = pk_bf16(t[0], t[1]);
        xbu[v * 2 + 1] = pk_bf16(t[2], t[3]);
    }
}

// ---- index width autodetect ----
__global__ void flag_k(const int* __restrict__ row, int* __restrict__ flag)
{
    if (threadIdx.x == 0 && blockIdx.x == 0) {
        int s = 0;
#pragma unroll
        for (int i = 1; i < 64; i += 2) s |= row[i];
        flag[0] = (s == 0) ? 1 : 0;
    }
}
__device__ inline int idx_at(const int* __restrict__ p, int e, int mode) {
    return p[mode ? (e << 1) : e];
}

// ---- bucket into 128B meta rows; 1 atomic/edge; t=6 dead (self overwrites) ----
__global__ void edge_k(const int* __restrict__ row, const int* __restrict__ col,
                       const int* __restrict__ et, const int* __restrict__ flag,
                       unsigned int* __restrict__ meta,
                       unsigned int* __restrict__ ovfcnt,
                       int* __restrict__ ovf, int* __restrict__ novf, int E, int N)
{
    int e = blockIdx.x * blockDim.x + threadIdx.x;
    if (e >= E) return;
    const int mode = flag[0];
    int r = idx_at(row, e, mode);
    int c = idx_at(col, e, mode);
    int t = idx_at(et,  e, mode);
    if ((unsigned)r >= (unsigned)N || (unsigned)c >= (unsigned)N || (unsigned)t >= 6u)
        return;
    unsigned pos = atomicAdd(&meta[(size_t)r * ROWW], 1u);
    if (pos < BUCKET_CAP) {
        meta[(size_t)r * ROWW + 1 + pos] = (unsigned)((c << 3) | t);
    } else {                                          // essentially never
        atomicAdd(&ovfcnt[r * 7 + t], 1u);
        ovf[atomicAdd(novf, 1)] = e;
    }
}

// ---- fused gather(xb)->means->LDS->GEMM(wp)->out + BN stats. ----
// 16 nodes/block, 8 waves (512 thr): 2 nodes/wave phase-1, 1 ntile/wave phase-2.
__global__ __launch_bounds__(512, 8) void fused_k(
    const unsigned int* __restrict__ meta, const unsigned int* __restrict__ ovfcnt,
    const unsigned int* __restrict__ xbu, const uint4* __restrict__ wpq,
    float* __restrict__ out, float* __restrict__ statsR, int N)
{
    __shared__ unsigned int cold[TNODES * LROW];   // 28928 B; 4 blocks/CU (wave cap)
    const int tid  = threadIdx.x;
    const int l    = tid & 63;
    const int wv   = tid >> 6;                     // 0..7
    const int quad = l >> 4, lr = l & 15;
    const int tile = blockIdx.x * TNODES;
    const int base = tile + wv * 2;

    // ================= phase 1: per-node type-means (2 nodes/wave) =========
    unsigned mv = 0, self = 0;
    if (base < N) {
        mv   = (l < ROWW) ? meta[(size_t)base * ROWW + l] : 0u;
        self = xbu[(size_t)base * 64 + l];
    }
#pragma unroll
    for (int i = 0; i < 2; ++i) {
        const int r = base + i;
        if (r < N) {
            const unsigned fl = __shfl(mv, 0);
            const int nE = __builtin_amdgcn_readfirstlane(
                               (int)min(fl, (unsigned)BUCKET_CAP));
            const unsigned sv   = self;
            const unsigned mcur = mv;

            float acc[6][2];
#pragma unroll
            for (int t = 0; t < 6; ++t) { acc[t][0] = 0.f; acc[t][1] = 0.f; }

            // batch 0: 8 clamped loads, branch-free single clause -> all in flight
            unsigned q[8]; int pj[8];
            if (nE > 0) {
#pragma unroll
                for (int j = 0; j < 8; ++j) {
                    pj[j] = (int)__shfl(mcur, 1 + min(j, nE - 1));
                    q[j]  = xbu[(size_t)(pj[j] >> 3) * 64 + l];
                }
            }
            // prefetch next node metadata under the edge-load latency
            if (i == 0 && r + 1 < N) {
                mv   = (l < ROWW) ? meta[(size_t)(r + 1) * ROWW + l] : 0u;
                self = xbu[(size_t)(r + 1) * 64 + l];
            }
            if (nE > 0) {
#pragma unroll
                for (int j = 0; j < 8; ++j) {
                    unsigned qq = (j < nE) ? q[j] : 0u;   // zeroed dup: adds 0
                    float lo = bflo(qq), hi = bfhi(qq);
                    switch (__builtin_amdgcn_readfirstlane(pj[j] & 7)) {
                        case 0: acc[0][0] += lo; acc[0][1] += hi; break;
                        case 1: acc[1][0] += lo; acc[1][1] += hi; break;
                        case 2: acc[2][0] += lo; acc[2][1] += hi; break;
                        case 3: acc[3][0] += lo; acc[3][1] += hi; break;
                        case 4: acc[4][0] += lo; acc[4][1] += hi; break;
                        default: acc[5][0] += lo; acc[5][1] += hi; break;
                    }
                }
                // rare tail: degree > 8
                for (int k = 8; k < nE; k += 8) {
                    const int rem = nE - k;
#pragma unroll
                    for (int j = 0; j < 8; ++j) {
                        pj[j] = (int)__shfl(mcur, 1 + k + min(j, rem - 1));
                        q[j]  = xbu[(size_t)(pj[j] >> 3) * 64 + l];
                    }
#pragma unroll
                    for (int j = 0; j < 8; ++j) {
                        unsigned qq = (j < rem) ? q[j] : 0u;
                        float lo = bflo(qq), hi = bfhi(qq);
                        switch (__builtin_amdgcn_readfirstlane(pj[j] & 7)) {
                            case 0: acc[0][0] += lo; acc[0][1] += hi; break;
                            case 1: acc[1][0] += lo; acc[1][1] += hi; break;
                            case 2: acc[2][0] += lo; acc[2][1] += hi; break;
                            case 3: acc[3][0] += lo; acc[3][1] += hi; break;
                            case 4: acc[4][0] += lo; acc[4][1] += hi; break;
                            default: acc[5][0] += lo; acc[5][1] += hi; break;
                        }
                    }
                }
            }

            // per-type counts: ballot over in-bucket payload lanes 1..nE
            const bool inb = (l >= 1) && (l < 1 + nE);
            int c0 = (int)__popcll(__ballot(inb && ((mcur & 7u) == 0u)));
            int c1 = (int)__popcll(__ballot(inb && ((mcur & 7u) == 1u)));
            int c2 = (int)__popcll(__ballot(inb && ((mcur & 7u) == 2u)));
            int c3 = (int)__popcll(__ballot(inb && ((mcur & 7u) == 3u)));
            int c4 = (int)__popcll(__ballot(inb && ((mcur & 7u) == 4u)));
            int c5 = (int)__popcll(__ballot(inb && ((mcur & 7u) == 5u)));
            if (fl > (unsigned)BUCKET_CAP) {        // essentially never (cold)
                c0 += (int)ovfcnt[r * 7 + 0]; c1 += (int)ovfcnt[r * 7 + 1];
                c2 += (int)ovfcnt[r * 7 + 2]; c3 += (int)ovfcnt[r * 7 + 3];
                c4 += (int)ovfcnt[r * 7 + 4]; c5 += (int)ovfcnt[r * 7 + 5];
            }
            const float iv0 = 1.0f / (float)max(c0, 1);
            const float iv1 = 1.0f / (float)max(c1, 1);
            const float iv2 = 1.0f / (float)max(c2, 1);
            const float iv3 = 1.0f / (float)max(c3, 1);
            const float iv4 = 1.0f / (float)max(c4, 1);
            const float iv5 = 1.0f / (float)max(c5, 1);

            // means -> LDS (bf16 pairs); self slot (t=6) = xb row verbatim
            const int mrow = (wv * 2 + i) * LROW;
            cold[mrow + 0 * 64 + l] = pk_bf16(acc[0][0] * iv0, acc[0][1] * iv0);
            cold[mrow + 1 * 64 + l] = pk_bf16(acc[1][0] * iv1, acc[1][1] * iv1);
            cold[mrow + 2 * 64 + l] = pk_bf16(acc[2][0] * iv2, acc[2][1] * iv2);
            cold[mrow + 3 * 64 + l] = pk_bf16(acc[3][0] * iv3, acc[3][1] * iv3);
            cold[mrow + 4 * 64 + l] = pk_bf16(acc[4][0] * iv4, acc[4][1] * iv4);
            cold[mrow + 5 * 64 + l] = pk_bf16(acc[5][0] * iv5, acc[5][1] * iv5);
            cold[mrow + 6 * 64 + l] = sv;
        }
    }
    __syncthreads();

    // ======== phase 2: [16,896] @ [896,16] per wave, 2 indep MFMA chains ====
    f32x4 oa0 = (f32x4){0.f, 0.f, 0.f, 0.f};
    f32x4 oa1 = (f32x4){0.f, 0.f, 0.f, 0.f};
#pragma unroll
    for (int t = 0; t < 4; ++t)
#pragma unroll
        for (int kc = 0; kc < 4; ++kc) {
            BFrag a, b;
            const int ko = t * 64 + kc * 16 + quad * 4;
            a.q = *(const uint4*)&cold[lr * LROW + ko];
            b.q = wpq[(size_t)(((t * 8 + wv) * 4 + kc) * 64) + l];
            oa0 = __builtin_amdgcn_mfma_f32_16x16x32_bf16(a.b, b.b, oa0, 0, 0, 0);
        }
#pragma unroll
    for (int t = 4; t < 7; ++t)
#pragma unroll
        for (int kc = 0; kc < 4; ++kc) {
            BFrag a, b;
            const int ko = t * 64 + kc * 16 + quad * 4;
            a.q = *(const uint4*)&cold[lr * LROW + ko];
            b.q = wpq[(size_t)(((t * 8 + wv) * 4 + kc) * 64) + l];
            oa1 = __builtin_amdgcn_mfma_f32_16x16x32_bf16(a.b, b.b, oa1, 0, 0, 0);
        }
    // epilogue + fused BN stats. C/D: col=lr -> ch=wv*16+lr, row=quad*4+j -> node
    float s = 0.f, s2 = 0.f;
    const int ch = wv * 16 + lr;
#pragma unroll
    for (int j = 0; j < 4; ++j) {
        int m = tile + quad * 4 + j;
        if (m < N) {
            float v = oa0[j] + oa1[j];
            out[(size_t)m * 128 + ch] = v;
            s += v; s2 += v * v;
        }
    }
    s  += __shfl_xor(s, 16);  s  += __shfl_xor(s, 32);   // reduce across quads
    s2 += __shfl_xor(s2, 16); s2 += __shfl_xor(s2, 32);
    if (l < 16) {
        float* st = statsR + (size_t)(blockIdx.x & 7) * 256;   // 8 replicas
        atomicAdd(&st[ch],       s);
        atomicAdd(&st[128 + ch], s2);
    }
}

// ---- overflow repair: matvec xb[c]@W[t]/cnt -> out AND stats (replica 0) ----
__global__ void ovf_k(const int* __restrict__ ovf, const int* __restrict__ novf,
                      const int* __restrict__ row, const int* __restrict__ col,
                      const int* __restrict__ et, const int* __restrict__ flag,
                      const unsigned int* __restrict__ xbu,
                      const unsigned int* __restrict__ meta,
                      const unsigned int* __restrict__ ovfcnt,
                      const float* __restrict__ w,
                      float* __restrict__ out, float* __restrict__ statsR,
                      int nwaves)
{
    const int n = novf[0];
    if (n == 0) return;
    const int mode = flag[0];
    const int l = threadIdx.x & 63;
    for (int i = (blockIdx.x * 256 + threadIdx.x) >> 6; i < n; i += nwaves) {
        int e = ovf[i];
        int r = idx_at(row, e, mode);
        int c = idx_at(col, e, mode);
        int t = idx_at(et,  e, mode);
        // exact count = in-bucket ballot + overflow count word
        unsigned mv = (l < ROWW) ? meta[(size_t)r * ROWW + l] : 0u;
        unsigned fl = __shfl(mv, 0);
        int nE = (int)min(fl, (unsigned)BUCKET_CAP);
        bool inb = (l >= 1) && (l < 1 + nE);
        int ct = (int)__popcll(__ballot(inb && ((int)(mv & 7u) == t)))
               + (int)ovfcnt[r * 7 + t];
        float inv = 1.0f / (float)max(ct, 1);
        float d0 = 0.f, d1 = 0.f;
        for (int k = 0; k < 64; ++k) {
            unsigned xv = xbu[(size_t)c * 64 + k];
            float xlo = bflo(xv), xhi = bfhi(xv);
            const float* wr = w + (size_t)(t * 128 + 2 * k) * 128;
            d0 += xlo * wr[2 * l]     + xhi * wr[128 + 2 * l];
            d1 += xlo * wr[2 * l + 1] + xhi * wr[128 + 2 * l + 1];
        }
        d0 *= inv; d1 *= inv;
        float olo = atomicAdd(&out[(size_t)r * 128 + 2 * l],     d0);
        float ohi = atomicAdd(&out[(size_t)r * 128 + 2 * l + 1], d1);
        atomicAdd(&statsR[2 * l],           d0);
        atomicAdd(&statsR[128 + 2 * l],     d0 * (2.f * olo + d0));
        atomicAdd(&statsR[2 * l + 1],       d1);
        atomicAdd(&statsR[128 + 2 * l + 1], d1 * (2.f * ohi + d1));
    }
}

// ---- BN finalize: sums 8 stat replicas; coalesced vec4; no LDS ----
__global__ __launch_bounds__(256) void norm_k(
    float* __restrict__ out, const float* __restrict__ statsR,
    const float* __restrict__ gamma, const float* __restrict__ beta, int N)
{
    const int c0 = (threadIdx.x * 4) & 127;     // grid stride is mult. of 128 elems
    const float invN = 1.0f / (float)N;
    f32x4 sc, bi;
#pragma unroll
    for (int j = 0; j < 4; ++j) {
        int c = c0 + j;
        float sm = 0.f, sq = 0.f;
#pragma unroll
        for (int rep = 0; rep < 8; ++rep) {
            sm += statsR[rep * 256 + c];
            sq += statsR[rep * 256 + 128 + c];
        }
        float mean = sm * invN;
        float var  = sq * invN - mean * mean;
        float s = gamma[c] * rsqrtf(var + 1e-5f);
        sc[j] = s; bi[j] = beta[c] - mean * s;
    }
    const size_t nv = (size_t)N * 32;           // vec4 count
    for (size_t v = (size_t)blockIdx.x * 256 + threadIdx.x; v < nv;
         v += (size_t)gridDim.x * 256) {
        f32x4 x = *(f32x4*)(out + v * 4);
#pragma unroll
        for (int j = 0; j < 4; ++j) x[j] = x[j] * sc[j] + bi[j];
        *(f32x4*)(out + v * 4) = x;
    }
}

extern "C" void kernel_launch(void* const* d_in, const int* in_sizes, int n_in,
                              void* d_out, int out_size, void* d_ws, size_t ws_size,
                              hipStream_t stream)
{
    const float* x     = (const float*)d_in[0];
    const int*   row   = (const int*)d_in[1];
    const int*   col   = (const int*)d_in[2];
    const int*   etype = (const int*)d_in[3];
    const float* w     = (const float*)d_in[4];
    const float* gamma = (const float*)d_in[5];
    const float* beta  = (const float*)d_in[6];
    float* out = (float*)d_out;

    const int N = in_sizes[0] / 128;   // 100000
    const int E = in_sizes[1];         // 700000

    char* ws = (char*)d_ws;
    unsigned int* xbu    = (unsigned int*)ws;                             // N*64 u32
    short8*       wp     = (short8*)(ws + (size_t)N * 256);               // 229376 B
    unsigned int* meta   = (unsigned int*)((char*)wp + 7 * 8 * 4 * 64 * 16); // N*32 u32
    unsigned int* ovfcnt = (unsigned int*)((char*)meta + (size_t)N * ROWW * 4); // 7N u32
    int*          ovf    = (int*)((char*)ovfcnt + (size_t)N * 7 * 4);     // E int
    float*        stats  = (float*)((char*)ovf + (size_t)E * 4);          // 8*256 f32
    int*          flag   = (int*)((char*)stats + 8 * 256 * 4);            // 1 int
    int*          novf   = flag + 1;                                      // 1 int

    hipMemsetAsync(meta,   0, (size_t)N * ROWW * 4, stream);
    hipMemsetAsync(ovfcnt, 0, (size_t)N * 7 * 4,    stream);
    hipMemsetAsync(stats,  0, 8 * 256 * 4 + 8,      stream);

    flag_k<<<1, 64, 0, stream>>>(row, flag);
    pack_w<<<(7 * 8 * 4 * 64 + 255) / 256, 256, 0, stream>>>(w, wp);
    pack_x<<<2048, 256, 0, stream>>>(x, xbu, (long)N * 32);
    edge_k<<<(E + 255) / 256, 256, 0, stream>>>(row, col, etype, flag,
                                                meta, ovfcnt, ovf, novf, E, N);
    fused_k<<<(N + TNODES - 1) / TNODES, 512, 0, stream>>>(meta, ovfcnt, xbu,
                                                           (const uint4*)wp, out,
                                                           stats, N);
    ovf_k<<<64, 256, 0, stream>>>(ovf, novf, row, col, etype, flag,
                                  xbu, meta, ovfcnt, w, out, stats, 256);
    norm_k<<<2048, 256, 0, stream>>>(out, stats, gamma, beta, N);
}

// Round 9
// 255.981 us; speedup vs baseline: 1.1058x; 1.0263x over previous
//
#include <hip/hip_runtime.h>
#include <hip/hip_bf16.h>

// GraphConvNorm: scatter-mean by (row*7+edge_type) -> [N,896]@[896,128] -> BatchNorm.
// N=100000, C=128, E=700000. x/w/gamma/beta f32, indices auto int32/int64, out f32.
// Invariant (r11/r13/r15): fused_k gather pinned at 102us / ~2.1 TB/s logical random-
// line service regardless of occupancy/geometry -> machine ceiling, stop touching.
// r16: the ~160us non-fused remainder models to ~95us of work -> ~60us is launch
// serialization. Merge {flag, pack_w, pack_x, edge_k} into ONE prep_k with
// block-range roles (edge blocks first = longest pole; pack_x/pack_w overlap under
// edge's latency-bound atomics). flag workspace deleted; ovf_k computes index-width
// mode inline (only runs when novf>0 ~ never). fused_k/norm_k unchanged from r15.
// ws: xb 25.6MB + wp 0.23 + meta 12.8MB + ovfcnt 2.8MB + ovf 2.8MB + stats 8KB.

typedef float  f32x4  __attribute__((ext_vector_type(4)));
typedef short  short8 __attribute__((ext_vector_type(8)));
typedef __bf16 bf16x8 __attribute__((ext_vector_type(8)));

union BFrag { uint4 q; short8 s; bf16x8 b; unsigned int u[4]; };

__device__ inline unsigned short f2bfbits(float f) {
    union { float f; unsigned int u; } v; v.f = f;
    unsigned int u = v.u;
    u += 0x7fffu + ((u >> 16) & 1u);   // RNE
    return (unsigned short)(u >> 16);
}
__device__ inline unsigned int pk_bf16(float lo, float hi) {
    float2 f; f.x = lo; f.y = hi;
    union { __hip_bfloat162 h; unsigned int u; } v;
    v.h = __float22bfloat162_rn(f);
    return v.u;
}
__device__ inline float bflo(unsigned int p) {
    union { unsigned int u; float f; } v; v.u = p << 16; return v.f;
}
__device__ inline float bfhi(unsigned int p) {
    union { unsigned int u; float f; } v; v.u = p & 0xffff0000u; return v.f;
}

#define BUCKET_CAP 31
#define ROWW 32          // meta row: w0 = fill, w1-31 = payload  (one 128B line)
#define LROW 452         // LDS row u32 (448 data + 4 pad)
#define TNODES 16
#define NPX 1024         // pack_x blocks inside prep_k

__device__ inline int idx_at(const int* __restrict__ p, int e, int mode) {
    return p[mode ? (e << 1) : e];
}

// ---- prep: one kernel, three block roles (overlapped by the scheduler) ----
// [0, nEB)            : edge bucketing (atomic append into 128B meta rows)
// [nEB, nEB+NPX)      : pack_x  (x f32 -> xbu bf16-pair u32, grid-stride)
// [nEB+NPX, +56)      : pack_w  (W -> MFMA B-frag bf16 order)
__global__ __launch_bounds__(256) void prep_k(
    const float* __restrict__ x, const int* __restrict__ row,
    const int* __restrict__ col, const int* __restrict__ et,
    const float* __restrict__ w,
    unsigned int* __restrict__ xbu, short8* __restrict__ wp,
    unsigned int* __restrict__ meta, unsigned int* __restrict__ ovfcnt,
    int* __restrict__ ovf, int* __restrict__ novf,
    int E, int N, int nEB)
{
    const int bid = blockIdx.x;
    const int tid = threadIdx.x;

    if (bid < nEB) {
        // ---------------- edge role ----------------
        // index-width autodetect (per wave; all lanes participate in __any)
        const int li = tid & 63;
        int vodd = (li < 32) ? row[2 * li + 1] : 0;
        const int mode = __any(vodd != 0) ? 0 : 1;

        const int e = bid * 256 + tid;
        if (e < E) {
            int r = idx_at(row, e, mode);
            int c = idx_at(col, e, mode);
            int t = idx_at(et,  e, mode);
            if ((unsigned)r < (unsigned)N && (unsigned)c < (unsigned)N &&
                (unsigned)t < 6u) {
                unsigned pos = atomicAdd(&meta[(size_t)r * ROWW], 1u);
                if (pos < BUCKET_CAP) {
                    meta[(size_t)r * ROWW + 1 + pos] = (unsigned)((c << 3) | t);
                } else {                              // essentially never
                    atomicAdd(&ovfcnt[r * 7 + t], 1u);
                    ovf[atomicAdd(novf, 1)] = e;
                }
            }
        }
    } else if (bid < nEB + NPX) {
        // ---------------- pack_x role ----------------
        const size_t total4 = (size_t)N * 32;
        for (size_t v = (size_t)(bid - nEB) * 256 + tid; v < total4;
             v += (size_t)NPX * 256) {
            f32x4 t = *(const f32x4*)(x + v * 4);
            xbu[v * 2]     = pk_bf16(t[0], t[1]);
            xbu[v * 2 + 1] = pk_bf16(t[2], t[3]);
        }
    } else {
        // ---------------- pack_w role ----------------
        int u = (bid - nEB - NPX) * 256 + tid;
        if (u < 7 * 8 * 4 * 64) {
            int lane = u & 63, kc = (u >> 6) & 3, nt = (u >> 8) & 7, t = u >> 11;
            int quad = lane >> 4, lr = lane & 15;
            short8 s;
#pragma unroll
            for (int j = 0; j < 8; ++j)
                s[j] = (short)f2bfbits(
                    w[(size_t)(t * 128 + kc * 32 + quad * 8 + j) * 128
                      + nt * 16 + lr]);
            wp[u] = s;
        }
    }
}

// ---- fused gather(xb)->means->LDS->GEMM(wp)->out + BN stats. ----
// 16 nodes/block, 8 waves (512 thr): 2 nodes/wave phase-1, 1 ntile/wave phase-2.
__global__ __launch_bounds__(512, 8) void fused_k(
    const unsigned int* __restrict__ meta, const unsigned int* __restrict__ ovfcnt,
    const unsigned int* __restrict__ xbu, const uint4* __restrict__ wpq,
    float* __restrict__ out, float* __restrict__ statsR, int N)
{
    __shared__ unsigned int cold[TNODES * LROW];   // 28928 B; 4 blocks/CU (wave cap)
    const int tid  = threadIdx.x;
    const int l    = tid & 63;
    const int wv   = tid >> 6;                     // 0..7
    const int quad = l >> 4, lr = l & 15;
    const int tile = blockIdx.x * TNODES;
    const int base = tile + wv * 2;

    // ================= phase 1: per-node type-means (2 nodes/wave) =========
    unsigned mv = 0, self = 0;
    if (base < N) {
        mv   = (l < ROWW) ? meta[(size_t)base * ROWW + l] : 0u;
        self = xbu[(size_t)base * 64 + l];
    }
#pragma unroll
    for (int i = 0; i < 2; ++i) {
        const int r = base + i;
        if (r < N) {
            const unsigned fl = __shfl(mv, 0);
            const int nE = __builtin_amdgcn_readfirstlane(
                               (int)min(fl, (unsigned)BUCKET_CAP));
            const unsigned sv   = self;
            const unsigned mcur = mv;

            float acc[6][2];
#pragma unroll
            for (int t = 0; t < 6; ++t) { acc[t][0] = 0.f; acc[t][1] = 0.f; }

            // batch 0: 8 clamped loads, branch-free single clause -> all in flight
            unsigned q[8]; int pj[8];
            if (nE > 0) {
#pragma unroll
                for (int j = 0; j < 8; ++j) {
                    pj[j] = (int)__shfl(mcur, 1 + min(j, nE - 1));
                    q[j]  = xbu[(size_t)(pj[j] >> 3) * 64 + l];
                }
            }
            // prefetch next node metadata under the edge-load latency
            if (i == 0 && r + 1 < N) {
                mv   = (l < ROWW) ? meta[(size_t)(r + 1) * ROWW + l] : 0u;
                self = xbu[(size_t)(r + 1) * 64 + l];
            }
            if (nE > 0) {
#pragma unroll
                for (int j = 0; j < 8; ++j) {
                    unsigned qq = (j < nE) ? q[j] : 0u;   // zeroed dup: adds 0
                    float lo = bflo(qq), hi = bfhi(qq);
                    switch (__builtin_amdgcn_readfirstlane(pj[j] & 7)) {
                        case 0: acc[0][0] += lo; acc[0][1] += hi; break;
                        case 1: acc[1][0] += lo; acc[1][1] += hi; break;
                        case 2: acc[2][0] += lo; acc[2][1] += hi; break;
                        case 3: acc[3][0] += lo; acc[3][1] += hi; break;
                        case 4: acc[4][0] += lo; acc[4][1] += hi; break;
                        default: acc[5][0] += lo; acc[5][1] += hi; break;
                    }
                }
                // rare tail: degree > 8
                for (int k = 8; k < nE; k += 8) {
                    const int rem = nE - k;
#pragma unroll
                    for (int j = 0; j < 8; ++j) {
                        pj[j] = (int)__shfl(mcur, 1 + k + min(j, rem - 1));
                        q[j]  = xbu[(size_t)(pj[j] >> 3) * 64 + l];
                    }
#pragma unroll
                    for (int j = 0; j < 8; ++j) {
                        unsigned qq = (j < rem) ? q[j] : 0u;
                        float lo = bflo(qq), hi = bfhi(qq);
                        switch (__builtin_amdgcn_readfirstlane(pj[j] & 7)) {
                            case 0: acc[0][0] += lo; acc[0][1] += hi; break;
                            case 1: acc[1][0] += lo; acc[1][1] += hi; break;
                            case 2: acc[2][0] += lo; acc[2][1] += hi; break;
                            case 3: acc[3][0] += lo; acc[3][1] += hi; break;
                            case 4: acc[4][0] += lo; acc[4][1] += hi; break;
                            default: acc[5][0] += lo; acc[5][1] += hi; break;
                        }
                    }
                }
            }

            // per-type counts: ballot over in-bucket payload lanes 1..nE
            const bool inb = (l >= 1) && (l < 1 + nE);
            int c0 = (int)__popcll(__ballot(inb && ((mcur & 7u) == 0u)));
            int c1 = (int)__popcll(__ballot(inb && ((mcur & 7u) == 1u)));
            int c2 = (int)__popcll(__ballot(inb && ((mcur & 7u) == 2u)));
            int c3 = (int)__popcll(__ballot(inb && ((mcur & 7u) == 3u)));
            int c4 = (int)__popcll(__ballot(inb && ((mcur & 7u) == 4u)));
            int c5 = (int)__popcll(__ballot(inb && ((mcur & 7u) == 5u)));
            if (fl > (unsigned)BUCKET_CAP) {        // essentially never (cold)
                c0 += (int)ovfcnt[r * 7 + 0]; c1 += (int)ovfcnt[r * 7 + 1];
                c2 += (int)ovfcnt[r * 7 + 2]; c3 += (int)ovfcnt[r * 7 + 3];
                c4 += (int)ovfcnt[r * 7 + 4]; c5 += (int)ovfcnt[r * 7 + 5];
            }
            const float iv0 = 1.0f / (float)max(c0, 1);
            const float iv1 = 1.0f / (float)max(c1, 1);
            const float iv2 = 1.0f / (float)max(c2, 1);
            const float iv3 = 1.0f / (float)max(c3, 1);
            const float iv4 = 1.0f / (float)max(c4, 1);
            const float iv5 = 1.0f / (float)max(c5, 1);

            // means -> LDS (bf16 pairs); self slot (t=6) = xb row verbatim
            const int mrow = (wv * 2 + i) * LROW;
            cold[mrow + 0 * 64 + l] = pk_bf16(acc[0][0] * iv0, acc[0][1] * iv0);
            cold[mrow + 1 * 64 + l] = pk_bf16(acc[1][0] * iv1, acc[1][1] * iv1);
            cold[mrow + 2 * 64 + l] = pk_bf16(acc[2][0] * iv2, acc[2][1] * iv2);
            cold[mrow + 3 * 64 + l] = pk_bf16(acc[3][0] * iv3, acc[3][1] * iv3);
            cold[mrow + 4 * 64 + l] = pk_bf16(acc[4][0] * iv4, acc[4][1] * iv4);
            cold[mrow + 5 * 64 + l] = pk_bf16(acc[5][0] * iv5, acc[5][1] * iv5);
            cold[mrow + 6 * 64 + l] = sv;
        }
    }
    __syncthreads();

    // ======== phase 2: [16,896] @ [896,16] per wave, 2 indep MFMA chains ====
    f32x4 oa0 = (f32x4){0.f, 0.f, 0.f, 0.f};
    f32x4 oa1 = (f32x4){0.f, 0.f, 0.f, 0.f};
#pragma unroll
    for (int t = 0; t < 4; ++t)
#pragma unroll
        for (int kc = 0; kc < 4; ++kc) {
            BFrag a, b;
            const int ko = t * 64 + kc * 16 + quad * 4;
            a.q = *(const uint4*)&cold[lr * LROW + ko];
            b.q = wpq[(size_t)(((t * 8 + wv) * 4 + kc) * 64) + l];
            oa0 = __builtin_amdgcn_mfma_f32_16x16x32_bf16(a.b, b.b, oa0, 0, 0, 0);
        }
#pragma unroll
    for (int t = 4; t < 7; ++t)
#pragma unroll
        for (int kc = 0; kc < 4; ++kc) {
            BFrag a, b;
            const int ko = t * 64 + kc * 16 + quad * 4;
            a.q = *(const uint4*)&cold[lr * LROW + ko];
            b.q = wpq[(size_t)(((t * 8 + wv) * 4 + kc) * 64) + l];
            oa1 = __builtin_amdgcn_mfma_f32_16x16x32_bf16(a.b, b.b, oa1, 0, 0, 0);
        }
    // epilogue + fused BN stats. C/D: col=lr -> ch=wv*16+lr, row=quad*4+j -> node
    float s = 0.f, s2 = 0.f;
    const int ch = wv * 16 + lr;
#pragma unroll
    for (int j = 0; j < 4; ++j) {
        int m = tile + quad * 4 + j;
        if (m < N) {
            float v = oa0[j] + oa1[j];
            out[(size_t)m * 128 + ch] = v;
            s += v; s2 += v * v;
        }
    }
    s  += __shfl_xor(s, 16);  s  += __shfl_xor(s, 32);   // reduce across quads
    s2 += __shfl_xor(s2, 16); s2 += __shfl_xor(s2, 32);
    if (l < 16) {
        float* st = statsR + (size_t)(blockIdx.x & 7) * 256;   // 8 replicas
        atomicAdd(&st[ch],       s);
        atomicAdd(&st[128 + ch], s2);
    }
}

// ---- overflow repair: matvec xb[c]@W[t]/cnt -> out AND stats (replica 0) ----
__global__ void ovf_k(const int* __restrict__ ovf, const int* __restrict__ novf,
                      const int* __restrict__ row, const int* __restrict__ col,
                      const int* __restrict__ et,
                      const unsigned int* __restrict__ xbu,
                      const unsigned int* __restrict__ meta,
                      const unsigned int* __restrict__ ovfcnt,
                      const float* __restrict__ w,
                      float* __restrict__ out, float* __restrict__ statsR,
                      int nwaves)
{
    const int n = novf[0];
    if (n == 0) return;
    // index-width autodetect (inline; only reached when n > 0)
    int s = 0;
#pragma unroll
    for (int i = 1; i < 64; i += 2) s |= row[i];
    const int mode = (s == 0) ? 1 : 0;
    const int l = threadIdx.x & 63;
    for (int i = (blockIdx.x * 256 + threadIdx.x) >> 6; i < n; i += nwaves) {
        int e = ovf[i];
        int r = idx_at(row, e, mode);
        int c = idx_at(col, e, mode);
        int t = idx_at(et,  e, mode);
        // exact count = in-bucket ballot + overflow count word
        unsigned mv = (l < ROWW) ? meta[(size_t)r * ROWW + l] : 0u;
        unsigned fl = __shfl(mv, 0);
        int nE = (int)min(fl, (unsigned)BUCKET_CAP);
        bool inb = (l >= 1) && (l < 1 + nE);
        int ct = (int)__popcll(__ballot(inb && ((int)(mv & 7u) == t)))
               + (int)ovfcnt[r * 7 + t];
        float inv = 1.0f / (float)max(ct, 1);
        float d0 = 0.f, d1 = 0.f;
        for (int k = 0; k < 64; ++k) {
            unsigned xv = xbu[(size_t)c * 64 + k];
            float xlo = bflo(xv), xhi = bfhi(xv);
            const float* wr = w + (size_t)(t * 128 + 2 * k) * 128;
            d0 += xlo * wr[2 * l]     + xhi * wr[128 + 2 * l];
            d1 += xlo * wr[2 * l + 1] + xhi * wr[128 + 2 * l + 1];
        }
        d0 *= inv; d1 *= inv;
        float olo = atomicAdd(&out[(size_t)r * 128 + 2 * l],     d0);
        float ohi = atomicAdd(&out[(size_t)r * 128 + 2 * l + 1], d1);
        atomicAdd(&statsR[2 * l],           d0);
        atomicAdd(&statsR[128 + 2 * l],     d0 * (2.f * olo + d0));
        atomicAdd(&statsR[2 * l + 1],       d1);
        atomicAdd(&statsR[128 + 2 * l + 1], d1 * (2.f * ohi + d1));
    }
}

// ---- BN finalize: sums 8 stat replicas; coalesced vec4; no LDS ----
__global__ __launch_bounds__(256) void norm_k(
    float* __restrict__ out, const float* __restrict__ statsR,
    const float* __restrict__ gamma, const float* __restrict__ beta, int N)
{
    const int c0 = (threadIdx.x * 4) & 127;     // grid stride is mult. of 128 elems
    const float invN = 1.0f / (float)N;
    f32x4 sc, bi;
#pragma unroll
    for (int j = 0; j < 4; ++j) {
        int c = c0 + j;
        float sm = 0.f, sq = 0.f;
#pragma unroll
        for (int rep = 0; rep < 8; ++rep) {
            sm += statsR[rep * 256 + c];
            sq += statsR[rep * 256 + 128 + c];
        }
        float mean = sm * invN;
        float var  = sq * invN - mean * mean;
        float s = gamma[c] * rsqrtf(var + 1e-5f);
        sc[j] = s; bi[j] = beta[c] - mean * s;
    }
    const size_t nv = (size_t)N * 32;           // vec4 count
    for (size_t v = (size_t)blockIdx.x * 256 + threadIdx.x; v < nv;
         v += (size_t)gridDim.x * 256) {
        f32x4 x = *(f32x4*)(out + v * 4);
#pragma unroll
        for (int j = 0; j < 4; ++j) x[j] = x[j] * sc[j] + bi[j];
        *(f32x4*)(out + v * 4) = x;
    }
}

extern "C" void kernel_launch(void* const* d_in, const int* in_sizes, int n_in,
                              void* d_out, int out_size, void* d_ws, size_t ws_size,
                              hipStream_t stream)
{
    const float* x     = (const float*)d_in[0];
    const int*   row   = (const int*)d_in[1];
    const int*   col   = (const int*)d_in[2];
    const int*   etype = (const int*)d_in[3];
    const float* w     = (const float*)d_in[4];
    const float* gamma = (const float*)d_in[5];
    const float* beta  = (const float*)d_in[6];
    float* out = (float*)d_out;

    const int N = in_sizes[0] / 128;   // 100000
    const int E = in_sizes[1];         // 700000

    char* ws = (char*)d_ws;
    unsigned int* xbu    = (unsigned int*)ws;                             // N*64 u32
    short8*       wp     = (short8*)(ws + (size_t)N * 256);               // 229376 B
    unsigned int* meta   = (unsigned int*)((char*)wp + 7 * 8 * 4 * 64 * 16); // N*32 u32
    unsigned int* ovfcnt = (unsigned int*)((char*)meta + (size_t)N * ROWW * 4); // 7N u32
    int*          ovf    = (int*)((char*)ovfcnt + (size_t)N * 7 * 4);     // E int
    float*        stats  = (float*)((char*)ovf + (size_t)E * 4);          // 8*256 f32
    int*          novf   = (int*)((char*)stats + 8 * 256 * 4);            // 1 int

    hipMemsetAsync(meta,   0, (size_t)N * ROWW * 4, stream);
    hipMemsetAsync(ovfcnt, 0, (size_t)N * 7 * 4,    stream);
    hipMemsetAsync(stats,  0, 8 * 256 * 4 + 8,      stream);

    const int nEB = (E + 255) / 256;             // edge blocks (longest pole first)
    const int nPW = (7 * 8 * 4 * 64 + 255) / 256; // 56 pack_w blocks
    prep_k<<<nEB + NPX + nPW, 256, 0, stream>>>(x, row, col, etype, w,
                                                xbu, wp, meta, ovfcnt,
                                                ovf, novf, E, N, nEB);
    fused_k<<<(N + TNODES - 1) / TNODES, 512, 0, stream>>>(meta, ovfcnt, xbu,
                                                           (const uint4*)wp, out,
                                                           stats, N);
    ovf_k<<<64, 256, 0, stream>>>(ovf, novf, row, col, etype,
                                  xbu, meta, ovfcnt, w, out, stats, 256);
    norm_k<<<2048, 256, 0, stream>>>(out, stats, gamma, beta, N);
}